// Round 6
// baseline (488.194 us; speedup 1.0000x reference)
//
#include <hip/hip_runtime.h>

// Problem: B=32, S=8192, U=1024, H=1024, axis=1.
// out[b,s,h] = (s - idx[b]) in [0,U) ? quant(updates[b, s-idx[b], h]) : input[b,s,h]
// quant(u) = clip(round(u / scale[h] + zp[h]), -128, 127), cast to int8.
// Harness dtypes: input -> int32*, indices -> int32*, updates -> float*,
// scales/zp -> float*, out -> int32*.
//
// Structure (best-known R2 marching order + branchless ILP):
//  - 2^19 threads (2048x256); each handles a fixed column group h (invariant),
//    16 B/lane, wave footprint = contiguous 1 KB per load instruction.
//  - Outer loop over b (32): idxs[b] is a wave-uniform scalar load, once.
//  - Inner 4 iterations fully unrolled: 4 independent loads in flight.
//  - Branchless: per-lane select of source pointer (input vs updates), one
//    dwordx4 load, always quantize, vector-select the result. Discarded
//    pointer is never dereferenced; bytes identical to R2.
//  - 1/scale hoisted (rcp-mul validated in R5: absmax 0.0; ties are +/-1
//    vs threshold 2.56).

typedef float f32x4 __attribute__((ext_vector_type(4)));
typedef int   i32x4 __attribute__((ext_vector_type(4)));

#define BB 32
#define SS 8192
#define UU 1024
#define HH 1024

__device__ __forceinline__ int quant1(float u, float r, float z) {
    float q = rintf(fmaf(u, r, z));
    q = fminf(fmaxf(q, -128.0f), 127.0f);   // -inf -> -128, +inf -> 127
    return (int)q;
}

__global__ __launch_bounds__(256) void scatter_quant_kernel(
        const int* __restrict__ inp,
        const int* __restrict__ idxs,
        const float* __restrict__ upd,
        const float* __restrict__ scales,
        const float* __restrict__ zps,
        int* __restrict__ out) {
    const int tid    = (int)blockIdx.x * 256 + (int)threadIdx.x;  // < 2^19
    const int h      = (tid & 255) << 2;   // column offset, invariant per thread
    const int rowpos = tid >> 8;           // 0..2047, row slot within window

    const f32x4 sc = *reinterpret_cast<const f32x4*>(scales + h);
    const f32x4 zp = *reinterpret_cast<const f32x4*>(zps + h);
    const f32x4 rc = { 1.0f / sc.x, 1.0f / sc.y, 1.0f / sc.z, 1.0f / sc.w };

    for (int b = 0; b < BB; ++b) {
        const int idx = idxs[b];                       // uniform -> s_load
        const long long gbase = ((long long)b << 21) + tid;      // group index
        const int* updb = reinterpret_cast<const int*>(upd)
                        + (((long long)b) << 20) + h;  // b*U*H + h

#pragma unroll
        for (int k = 0; k < 4; ++k) {
            const int s = (k << 11) + rowpos;          // row within batch
            const unsigned urow = (unsigned)(s - idx);
            const bool isupd = urow < (unsigned)UU;
            const long long eoff = (gbase + ((long long)k << 19)) << 2;

            const int* src = isupd
                ? (updb + ((int)(urow & (UU - 1)) << 10))
                : (inp + eoff);
            const i32x4 v = *reinterpret_cast<const i32x4*>(src);
            const f32x4 u = __builtin_bit_cast(f32x4, v);

            i32x4 q;
            q.x = quant1(u.x, rc.x, zp.x);
            q.y = quant1(u.y, rc.y, zp.y);
            q.z = quant1(u.z, rc.z, zp.z);
            q.w = quant1(u.w, rc.w, zp.w);

            const i32x4 o = isupd ? q : v;
            *reinterpret_cast<i32x4*>(out + eoff) = o;
        }
    }
}

extern "C" void kernel_launch(void* const* d_in, const int* in_sizes, int n_in,
                              void* d_out, int out_size, void* d_ws, size_t ws_size,
                              hipStream_t stream) {
    const int*   inp    = (const int*)d_in[0];
    const int*   idxs   = (const int*)d_in[1];
    const float* upd    = (const float*)d_in[2];
    const float* scales = (const float*)d_in[3];
    const float* zps    = (const float*)d_in[4];
    int*         out    = (int*)d_out;

    scatter_quant_kernel<<<2048, 256, 0, stream>>>(inp, idxs, upd, scales, zps, out);
}

// Round 7
// 447.121 us; speedup vs baseline: 1.0919x; 1.0919x over previous
//
#include <hip/hip_runtime.h>

// Problem: B=32, S=8192, U=1024, H=1024, axis=1.
// out[b,s,h] = (s - idx[b]) in [0,U) ? quant(updates[b, s-idx[b], h]) : input[b,s,h]
// quant(u) = clip(round(u / scale[h] + zp[h]), -128, 127), cast to int8.
// Harness dtypes: input -> int32*, indices -> int32*, updates -> float*,
// scales/zp -> float*, out -> int32*.
//
// R2 exact structure + ONE change: idxs[b] hoisted to a per-b scalar load.
// R2's grid-stride loop visits i = tid + t*2^19, which decomposes as
// b = t>>2 (outer), s = (t&3)*2048 + (tid>>8), h = (tid&255)*4 — so looping
// b outer / t inner (rolled) reproduces R2's address sequence exactly while
// loading idxs[b] once per batch (32 s_loads total vs 128 VMEM loads/thread).
// Body kept minimal (branchy, 1 load + 1 store, low VGPR) — R6 showed the
// fat branchless/unrolled body costs 22%.

typedef float f32x4 __attribute__((ext_vector_type(4)));
typedef int   i32x4 __attribute__((ext_vector_type(4)));

#define BB 32
#define SS 8192
#define UU 1024
#define HH 1024

__device__ __forceinline__ int quant1(float u, float r, float z) {
    float q = rintf(fmaf(u, r, z));
    q = fminf(fmaxf(q, -128.0f), 127.0f);   // -inf -> -128, +inf -> 127
    return (int)q;
}

__global__ __launch_bounds__(256) void scatter_quant_kernel(
        const int* __restrict__ inp,
        const int* __restrict__ idxs,
        const float* __restrict__ upd,
        const float* __restrict__ scales,
        const float* __restrict__ zps,
        int* __restrict__ out) {
    const int tid     = (int)blockIdx.x * 256 + (int)threadIdx.x;  // < 2^19
    const int h       = (tid & 255) << 2;   // column offset, invariant
    const int rowslot = tid >> 8;           // 0..2047 (block-uniform)

    const f32x4 sc = *reinterpret_cast<const f32x4*>(scales + h);
    const f32x4 zp = *reinterpret_cast<const f32x4*>(zps + h);
    const f32x4 rc = { 1.0f / sc.x, 1.0f / sc.y, 1.0f / sc.z, 1.0f / sc.w };

    for (int b = 0; b < BB; ++b) {
        const int idx = idxs[b];            // uniform loop index -> s_load, 1/batch
        const long long bbase = ((long long)b << 23) + h;   // b*S*H + h
        const float* updb = upd + (((long long)b) << 20) + h;

#pragma unroll 1
        for (int t = 0; t < 4; ++t) {
            const int s = (t << 11) + rowslot;
            const unsigned urow = (unsigned)(s - idx);
            const long long off = bbase + ((long long)s << 10);

            i32x4 o;
            if (urow < (unsigned)UU) {
                const f32x4 u = *reinterpret_cast<const f32x4*>(
                    updb + ((long long)urow << 10));
                o.x = quant1(u.x, rc.x, zp.x);
                o.y = quant1(u.y, rc.y, zp.y);
                o.z = quant1(u.z, rc.z, zp.z);
                o.w = quant1(u.w, rc.w, zp.w);
            } else {
                o = *reinterpret_cast<const i32x4*>(inp + off);
            }
            *reinterpret_cast<i32x4*>(out + off) = o;
        }
    }
}

extern "C" void kernel_launch(void* const* d_in, const int* in_sizes, int n_in,
                              void* d_out, int out_size, void* d_ws, size_t ws_size,
                              hipStream_t stream) {
    const int*   inp    = (const int*)d_in[0];
    const int*   idxs   = (const int*)d_in[1];
    const float* upd    = (const float*)d_in[2];
    const float* scales = (const float*)d_in[3];
    const float* zps    = (const float*)d_in[4];
    int*         out    = (int*)d_out;

    scatter_quant_kernel<<<2048, 256, 0, stream>>>(inp, idxs, upd, scales, zps, out);
}

// Round 8
// 433.860 us; speedup vs baseline: 1.1252x; 1.0306x over previous
//
#include <hip/hip_runtime.h>

// Problem: B=32, S=8192, U=1024, H=1024, axis=1.
// out[b,s,h] = (s - idx[b]) in [0,U) ? quant(updates[b, s-idx[b], h]) : input[b,s,h]
// quant(u) = clip(round(u / scale[h] + zp[h]), -128, 127), cast to int8.
// Harness dtypes: input -> int32*, indices -> int32*, updates -> float*,
// scales/zp -> float*, out -> int32*.
//
// Phase-split grid (rows are disjoint, single kernel, no ordering needed):
//  - Blocks [0,1792): copy the 7168 non-updated rows of each batch.
//    Non-updated rows are [0,idx) u [idx+U,S): phys = r + (r>=idx ? U : 0).
//    All row math is SCALAR (b = t>>2 uniform, r block-uniform, idx s_load);
//    the per-lane work is exactly one dwordx4 load + one dwordx4 store with
//    an invariant lane offset -> memcpy-shaped inner loop (m13 pattern).
//    Marching order preserved from R2: one sequential window, batch by batch.
//  - Blocks [1792,2048): quantize the U=1024 updated rows per batch
//    (8 blocks x 128 rows each): read updates, quant, write out. No input
//    read, no branch.
// Total bytes = 0.94r + 0.134r + 1.07w = 2.147 GB = the true minimum.

typedef float f32x4 __attribute__((ext_vector_type(4)));
typedef int   i32x4 __attribute__((ext_vector_type(4)));

#define BB 32
#define SS 8192
#define UU 1024
#define HH 1024
#define NB1 1792              // phase-1 blocks; 7168 = 4*1792 rows/batch
#define ROWS_NU 7168          // S - U

__device__ __forceinline__ int quant1(float u, float r, float z) {
    float q = rintf(fmaf(u, r, z));
    q = fminf(fmaxf(q, -128.0f), 127.0f);   // -inf -> -128, +inf -> 127
    return (int)q;
}

__global__ __launch_bounds__(256) void scatter_quant_kernel(
        const int* __restrict__ inp,
        const int* __restrict__ idxs,
        const float* __restrict__ upd,
        const float* __restrict__ scales,
        const float* __restrict__ zps,
        int* __restrict__ out) {
    const int g        = (int)blockIdx.x;
    const int lane_off = (int)threadIdx.x << 2;   // invariant elem offset in row

    if (g < NB1) {
        // ---- Phase 1: pure copy of non-updated rows ----
        for (int t = 0; t < 128; ++t) {
            const int b   = t >> 2;                      // uniform scalar
            const int idx = idxs[b];                     // s_load
            const int r   = (t & 3) * NB1 + g;           // block-uniform scalar
            const int phys = r + (r >= idx ? UU : 0);    // s_cselect
            const long long e = ((((long long)b << 13) + phys) << 10) + lane_off;
            *reinterpret_cast<i32x4*>(out + e) =
                *reinterpret_cast<const i32x4*>(inp + e);
        }
    } else {
        // ---- Phase 2: quantize updated rows ----
        const int k   = g - NB1;        // 0..255
        const int b   = k >> 3;
        const int sub = k & 7;
        const int idx = idxs[b];        // scalar

        const f32x4 sc = *reinterpret_cast<const f32x4*>(scales + lane_off);
        const f32x4 zp = *reinterpret_cast<const f32x4*>(zps + lane_off);
        const f32x4 rc = { 1.0f / sc.x, 1.0f / sc.y, 1.0f / sc.z, 1.0f / sc.w };

        const float* updb = upd + ((long long)b << 20) + lane_off;
        int* outb = out + ((((long long)b << 13) + idx) << 10) + lane_off;

        for (int t = 0; t < 128; ++t) {
            const int u = (sub << 7) + t;                // row within update block
            const f32x4 v = *reinterpret_cast<const f32x4*>(
                updb + ((long long)u << 10));
            i32x4 q;
            q.x = quant1(v.x, rc.x, zp.x);
            q.y = quant1(v.y, rc.y, zp.y);
            q.z = quant1(v.z, rc.z, zp.z);
            q.w = quant1(v.w, rc.w, zp.w);
            *reinterpret_cast<i32x4*>(outb + ((long long)u << 10)) = q;
        }
    }
}

extern "C" void kernel_launch(void* const* d_in, const int* in_sizes, int n_in,
                              void* d_out, int out_size, void* d_ws, size_t ws_size,
                              hipStream_t stream) {
    const int*   inp    = (const int*)d_in[0];
    const int*   idxs   = (const int*)d_in[1];
    const float* upd    = (const float*)d_in[2];
    const float* scales = (const float*)d_in[3];
    const float* zps    = (const float*)d_in[4];
    int*         out    = (int*)d_out;

    scatter_quant_kernel<<<2048, 256, 0, stream>>>(inp, idxs, upd, scales, zps, out);
}

// Round 9
// 406.035 us; speedup vs baseline: 1.2023x; 1.0685x over previous
//
#include <hip/hip_runtime.h>

// Problem: B=32, S=8192, U=1024, H=1024, axis=1.
// out[b,s,h] = (s - idx[b]) in [0,U) ? quant(updates[b, s-idx[b], h]) : input[b,s,h]
// quant(u) = clip(round_half_even(u / scale[h] + zp[h]), -128, 127), cast to int8.
// Harness dtypes: input -> int32*, indices -> int32*, updates -> float*,
// scales/zp -> float*, out -> int32*.
//
// This is the round-2 kernel (400.8 us, best of 7 structures tested) with
// exactly ONE change: #pragma unroll 2 on the grid-stride loop, so two
// independent 16B load/store pairs are in flight per thread and the compiler
// can cluster loads ahead of stores (fewer DRAM bus turnarounds).
// Every heavier restructure (region ownership, nt hints, branchless,
// scalarized idx, phase split) measured 434-488 us.

#define BB 32
#define SS 8192
#define UU 1024
#define HH 1024

// S*H/4 = 2^21 int4-groups per batch; H/4 = 256 groups per row.
#define ROW_G 256            // H/4
#define BATCH_G (SS * ROW_G) // 2^21

__device__ __forceinline__ int quant1(float u, float sc, float zp) {
    float q = rintf(u / sc + zp);          // round half-to-even, matches jnp.round
    q = fmaxf(q, -128.0f);                 // fmaxf(-inf,-128) = -128  (neginf case)
    q = fminf(q, 127.0f);                  // fminf(+inf, 127) = 127  (posinf case)
    return (int)q;                         // value already integral, in [-128,127]
}

__global__ void scatter_quant_kernel(const int* __restrict__ inp,
                                     const int* __restrict__ idxs,
                                     const float* __restrict__ upd,
                                     const float* __restrict__ scales,
                                     const float* __restrict__ zps,
                                     int* __restrict__ out,
                                     long long n4) {
    long long stride = (long long)gridDim.x * blockDim.x;
#pragma unroll 2
    for (long long i = (long long)blockIdx.x * blockDim.x + threadIdx.x;
         i < n4; i += stride) {
        int b  = (int)(i >> 21);               // / BATCH_G
        int r  = (int)(i & (BATCH_G - 1));
        int s  = r >> 8;                       // / ROW_G
        int h4 = r & (ROW_G - 1);

        int idx = idxs[b];                     // 32 values, L1/L2 resident
        unsigned urow = (unsigned)(s - idx);

        int4 o;
        if (urow < (unsigned)UU) {
            const float4 u4 = *reinterpret_cast<const float4*>(
                upd + (((long long)b * UU + urow) * HH + (h4 << 2)));
            const float4 sc = *reinterpret_cast<const float4*>(scales + (h4 << 2));
            const float4 zp = *reinterpret_cast<const float4*>(zps + (h4 << 2));
            o.x = quant1(u4.x, sc.x, zp.x);
            o.y = quant1(u4.y, sc.y, zp.y);
            o.z = quant1(u4.z, sc.z, zp.z);
            o.w = quant1(u4.w, sc.w, zp.w);
        } else {
            o = *reinterpret_cast<const int4*>(inp + (i << 2));
        }
        *reinterpret_cast<int4*>(out + (i << 2)) = o;
    }
}

extern "C" void kernel_launch(void* const* d_in, const int* in_sizes, int n_in,
                              void* d_out, int out_size, void* d_ws, size_t ws_size,
                              hipStream_t stream) {
    const int*   inp    = (const int*)d_in[0];
    const int*   idxs   = (const int*)d_in[1];
    const float* upd    = (const float*)d_in[2];
    const float* scales = (const float*)d_in[3];
    const float* zps    = (const float*)d_in[4];
    int*         out    = (int*)d_out;

    const long long n4 = (long long)BB * SS * (HH / 4);   // 67,108,864
    const int block = 256;
    const int grid  = 2048;   // grid-stride; ~128 iters/thread
    scatter_quant_kernel<<<grid, block, 0, stream>>>(inp, idxs, upd, scales, zps, out, n4);
}

// Round 10
// 399.067 us; speedup vs baseline: 1.2233x; 1.0175x over previous
//
#include <hip/hip_runtime.h>

// Problem: B=32, S=8192, U=1024, H=1024, axis=1.
// out[b,s,h] = (s - idx[b]) in [0,U) ? quant(updates[b, s-idx[b], h]) : input[b,s,h]
// quant(u) = clip(round_half_even(u / scale[h] + zp[h]), -128, 127), cast to int8.
// Harness dtypes: input -> int32*, indices -> int32*, updates -> float*,
// scales/zp -> float*, out -> int32*.
//
// FINAL: exact round-2 kernel — best of 8 structures tested (400.8 us,
// 5.36 TB/s on the minimal 2.147 GB traffic = 85% of the 6.29 TB/s copy
// ceiling). Eliminated by measurement: nontemporal hints (473), interleaved
// 32B lanes (434), branchless+unroll4 (488), b-outer scalarized idx (447),
// phase-split copy/quant grid (434), unroll2 (406). The residual ~15% is the
// mixed 3-stream R/W DRAM behavior, not kernel instruction overhead.

#define BB 32
#define SS 8192
#define UU 1024
#define HH 1024

// S*H/4 = 2^21 int4-groups per batch; H/4 = 256 groups per row.
#define ROW_G 256            // H/4
#define BATCH_G (SS * ROW_G) // 2^21

__device__ __forceinline__ int quant1(float u, float sc, float zp) {
    float q = rintf(u / sc + zp);          // round half-to-even, matches jnp.round
    q = fmaxf(q, -128.0f);                 // fmaxf(-inf,-128) = -128  (neginf case)
    q = fminf(q, 127.0f);                  // fminf(+inf, 127) = 127  (posinf case)
    return (int)q;                         // value already integral, in [-128,127]
}

__global__ void scatter_quant_kernel(const int* __restrict__ inp,
                                     const int* __restrict__ idxs,
                                     const float* __restrict__ upd,
                                     const float* __restrict__ scales,
                                     const float* __restrict__ zps,
                                     int* __restrict__ out,
                                     long long n4) {
    long long stride = (long long)gridDim.x * blockDim.x;
    for (long long i = (long long)blockIdx.x * blockDim.x + threadIdx.x;
         i < n4; i += stride) {
        int b  = (int)(i >> 21);               // / BATCH_G
        int r  = (int)(i & (BATCH_G - 1));
        int s  = r >> 8;                       // / ROW_G
        int h4 = r & (ROW_G - 1);

        int idx = idxs[b];                     // 32 values, L1/L2 resident
        unsigned urow = (unsigned)(s - idx);

        int4 o;
        if (urow < (unsigned)UU) {
            const float4 u4 = *reinterpret_cast<const float4*>(
                upd + (((long long)b * UU + urow) * HH + (h4 << 2)));
            const float4 sc = *reinterpret_cast<const float4*>(scales + (h4 << 2));
            const float4 zp = *reinterpret_cast<const float4*>(zps + (h4 << 2));
            o.x = quant1(u4.x, sc.x, zp.x);
            o.y = quant1(u4.y, sc.y, zp.y);
            o.z = quant1(u4.z, sc.z, zp.z);
            o.w = quant1(u4.w, sc.w, zp.w);
        } else {
            o = *reinterpret_cast<const int4*>(inp + (i << 2));
        }
        *reinterpret_cast<int4*>(out + (i << 2)) = o;
    }
}

extern "C" void kernel_launch(void* const* d_in, const int* in_sizes, int n_in,
                              void* d_out, int out_size, void* d_ws, size_t ws_size,
                              hipStream_t stream) {
    const int*   inp    = (const int*)d_in[0];
    const int*   idxs   = (const int*)d_in[1];
    const float* upd    = (const float*)d_in[2];
    const float* scales = (const float*)d_in[3];
    const float* zps    = (const float*)d_in[4];
    int*         out    = (int*)d_out;

    const long long n4 = (long long)BB * SS * (HH / 4);   // 67,108,864
    const int block = 256;
    const int grid  = 2048;   // grid-stride; ~128 iters/thread
    scatter_quant_kernel<<<grid, block, 0, stream>>>(inp, idxs, upd, scales, zps, out, n4);
}